// Round 6
// baseline (524.353 us; speedup 1.0000x reference)
//
#include <hip/hip_runtime.h>
#include <float.h>

// B_=1024 windows, N=64, M=128, H=8, D=32, DIM=256, nW=256
// rel bias index: rel = n - m + 128 in [1,191]
// masks: wi in {0,1} -> mask_left[wi], wi in {254,255} -> mask_right[wi-254]

typedef __attribute__((ext_vector_type(8))) short bf16x8;
typedef __attribute__((ext_vector_type(4))) float f32x4;

static __device__ __forceinline__ unsigned int f2bf(float f) {
    unsigned int u = __float_as_uint(f);
    return (u + 0x7FFFu + ((u >> 16) & 1u)) >> 16;  // RNE
}
static __device__ __forceinline__ unsigned int pack2(float lo, float hi) {
    return f2bf(lo) | (f2bf(hi) << 16);
}

// Transposed bf16 weights: [col][k], q @0 (256x256), kv @65536 (512x256), proj @196608 (256x256)
__device__ unsigned short g_Wt[262144];

__global__ __launch_bounds__(256) void prep_wt(
    const float* __restrict__ q_w, const float* __restrict__ kv_w, const float* __restrict__ proj_w)
{
    const int b = blockIdx.x, k = threadIdx.x;
    float v; unsigned short* dst;
    if (b < 256)      { v = q_w[k * 256 + b];            dst = g_Wt + b * 256; }
    else if (b < 768) { v = kv_w[k * 512 + (b - 256)];   dst = g_Wt + 65536 + (b - 256) * 256; }
    else              { v = proj_w[k * 256 + (b - 768)]; dst = g_Wt + 196608 + (b - 768) * 256; }
    dst[k] = (unsigned short)f2bf(v);
}

// ---------- stream-A MFMA GEMM: C[rows x NC] = A[rows x 256] @ W + bias ----------
// One block per 128-row tile, ALL NC columns -> A fetched exactly once from HBM.
// A in LDS (64 KB, XOR-swizzled); B-fragments read directly from L2-resident g_Wt
// ([col][k] layout -> each lane's fragment is one contiguous 16-B global load).
// 512 threads = 8 waves, wave owns 16 rows; A-frags hoisted to registers across col-slices.
template<int NC, int WT_OFF, bool ABF16, bool F32OUT>
__global__ __launch_bounds__(512) void gemm_sa(
    const void* __restrict__ Ain, const float* __restrict__ bias, void* __restrict__ Cout)
{
    __shared__ __align__(16) unsigned short As[128 * 256];   // 64 KB
    const size_t r0 = (size_t)blockIdx.x * 128;
    const int t = threadIdx.x;
    const int wave = t >> 6, lane = t & 63;
    const int lr = lane & 15, hi = lane >> 4;
    const int rw = wave * 16;                                 // wave's 16 rows

    // stage A: thread -> row=t>>2, quarter a=t&3; swizzle byte ^= ((row&7)<<4)
    {
        const int row = t >> 2, a = t & 3;
        char* dst = (char*)As + row * 512;
        const int swz = (row & 7) << 4;
        if (ABF16) {
            const unsigned short* src = (const unsigned short*)Ain + (r0 + row) * 256;
            #pragma unroll
            for (int i = 0; i < 8; ++i) {
                const int k = 8 * a + 32 * i;
                const uint4 v = *(const uint4*)(src + k);
                *(uint4*)(dst + ((2 * k) ^ swz)) = v;
            }
        } else {
            const float* src = (const float*)Ain + (r0 + row) * 256;
            #pragma unroll
            for (int i = 0; i < 16; ++i) {
                const int k = 4 * a + 16 * i;
                const float4 v = *(const float4*)(src + k);
                uint2 u; u.x = pack2(v.x, v.y); u.y = pack2(v.z, v.w);
                *(uint2*)(dst + ((2 * k) ^ swz)) = u;
            }
        }
    }
    __syncthreads();

    // hoist A-fragments: af[kk] = rows rw+lr, k = kk*32 + hi*8 .. +7   (row&7 == lr&7)
    bf16x8 af[8];
    {
        const char* arow = (const char*)As + (rw + lr) * 512;
        const int swzr = (lr & 7) << 4;
        #pragma unroll
        for (int kk = 0; kk < 8; ++kk)
            af[kk] = *(const bf16x8*)(arow + ((64 * kk + 16 * hi) ^ swzr));
    }

    #pragma unroll
    for (int cs = 0; cs < NC / 128; ++cs) {
        const int c0 = cs * 128;
        f32x4 acc[8];
        #pragma unroll
        for (int bj = 0; bj < 8; ++bj) acc[bj] = (f32x4){0.f, 0.f, 0.f, 0.f};

        // B-frag base for this lane: col = c0 + bj*16 + lr, k = kk*32 + hi*8
        const unsigned short* wb = g_Wt + WT_OFF + (size_t)(c0 + lr) * 256 + hi * 8;
        #pragma unroll
        for (int kk = 0; kk < 8; ++kk) {
            #pragma unroll
            for (int bj = 0; bj < 8; ++bj) {
                const bf16x8 bfr = *(const bf16x8*)(wb + bj * (16 * 256) + kk * 32);
                acc[bj] = __builtin_amdgcn_mfma_f32_16x16x32_bf16(af[kk], bfr, acc[bj], 0, 0, 0);
            }
        }

        // epilogue: row = rw + 4*hi + q, col = c0 + bj*16 + lr
        #pragma unroll
        for (int bj = 0; bj < 8; ++bj) {
            const int col = c0 + bj * 16 + lr;
            const float bb = bias[col];
            #pragma unroll
            for (int q = 0; q < 4; ++q) {
                const size_t row = r0 + rw + 4 * hi + q;
                const float val = acc[bj][q] + bb;
                if (F32OUT) ((float*)Cout)[row * NC + col] = val;
                else        ((unsigned short*)Cout)[row * NC + col] = (unsigned short)f2bf(val);
            }
        }
    }
}

// ---------- fused MFMA attention: one block per WINDOW, loop over 8 heads ----------
// Writes bf16 attn output back into the q buffer region (block-local rows -> race-free).
__global__ __launch_bounds__(256) void attn_fused(
    const unsigned short* __restrict__ qbf, const unsigned short* __restrict__ kvbf,
    const float* __restrict__ bias_table, const int* __restrict__ mask_left,
    const int* __restrict__ mask_right, unsigned short* __restrict__ aout)
{
    __shared__ __align__(16) unsigned short Qn[64 * 32];    // [n][d] natural
    __shared__ __align__(16) unsigned short Kn[128 * 32];   // [m][d] natural
    __shared__ __align__(16) unsigned short Vt[32 * 128];   // [d][m], swizzled ^((d&7)<<4)
    __shared__ __align__(16) unsigned short Pn[64 * 128];   // [n][m], swizzled ^((n&7)<<4)
    __shared__ float ballT[8 * 192];                        // bias table [h][rel]

    const int w = blockIdx.x;
    const int t = threadIdx.x;
    const int wave = t >> 6, lane = t & 63;
    const int lr = lane & 15, hi = lane >> 4;
    const int n0w = wave * 16;

    for (int i = t; i < 1536; i += 256) {
        const int hh = i / 192, r = i - hh * 192;
        ballT[i] = bias_table[r * 8 + hh];
    }

    const int wi = w & 255;
    const int* mbase = nullptr;
    if (wi < 2) mbase = mask_left + wi * (64 * 128);
    else if (wi >= 254) mbase = mask_right + (wi - 254) * (64 * 128);

    const float scale = 0.17677669529663687f;  // 32^-0.5

    for (int h = 0; h < 8; ++h) {
        __syncthreads();   // prior iteration's LDS reads complete (and ballT before first use)
        {   // stage Q head-slice: [64][32]
            const int n = t >> 2, dq = t & 3;
            const uint4 v = *(const uint4*)(qbf + ((size_t)(w * 64 + n)) * 256 + h * 32 + dq * 8);
            *(uint4*)((char*)Qn + n * 64 + dq * 16) = v;
        }
        #pragma unroll
        for (int i = 0; i < 2; ++i) {   // stage K: [128][32]
            const int m = (t >> 2) + 64 * i, dq = t & 3;
            const uint4 v = *(const uint4*)(kvbf + ((size_t)(w * 128 + m)) * 512 + h * 32 + dq * 8);
            *(uint4*)((char*)Kn + m * 64 + dq * 16) = v;
        }
        #pragma unroll
        for (int i = 0; i < 2; ++i) {   // stage V transposed: Vt[d][m] swizzled
            const int db = (t >> 7) * 2 + i, m = t & 127;
            const uint4 v = *(const uint4*)(kvbf + ((size_t)(w * 128 + m)) * 512 + 256 + h * 32 + db * 8);
            const unsigned short* vs = (const unsigned short*)&v;
            #pragma unroll
            for (int e = 0; e < 8; ++e) {
                const int d = db * 8 + e;
                *(unsigned short*)((char*)Vt + d * 256 + ((2 * m) ^ ((d & 7) << 4))) = vs[e];
            }
        }
        __syncthreads();

        // S = Q K^T : wave handles rows n0w..n0w+15, all 128 cols
        const bf16x8 qa = *(const bf16x8*)((char*)Qn + (n0w + lr) * 64 + 16 * hi);
        f32x4 sacc[8];
        #pragma unroll
        for (int mj = 0; mj < 8; ++mj) {
            sacc[mj] = (f32x4){0.f, 0.f, 0.f, 0.f};
            const bf16x8 kb = *(const bf16x8*)((char*)Kn + (mj * 16 + lr) * 64 + 16 * hi);
            sacc[mj] = __builtin_amdgcn_mfma_f32_16x16x32_bf16(qa, kb, sacc[mj], 0, 0, 0);
        }

        // epilogue on C-layout: row n = n0w + 4*hi + q, col m = 16*mj + lr
        const float* bh = ballT + h * 192;
        #pragma unroll
        for (int mj = 0; mj < 8; ++mj) {
            const int m = 16 * mj + lr;
            #pragma unroll
            for (int q = 0; q < 4; ++q) {
                const int n = n0w + 4 * hi + q;
                sacc[mj][q] = fmaf(sacc[mj][q], scale, bh[n - m + 128]);
            }
        }
        if (mbase) {
            #pragma unroll
            for (int mj = 0; mj < 8; ++mj) {
                const int m = 16 * mj + lr;
                #pragma unroll
                for (int q = 0; q < 4; ++q) {
                    const int n = n0w + 4 * hi + q;
                    if (mbase[n * 128 + m] == 1) sacc[mj][q] = -FLT_MAX;
                }
            }
        }

        // softmax over m (per row): row lives in 16 lanes sharing hi -> shfl_xor 1,2,4,8
        float inv[4];
        #pragma unroll
        for (int q = 0; q < 4; ++q) {
            float mx = sacc[0][q];
            #pragma unroll
            for (int mj = 1; mj < 8; ++mj) mx = fmaxf(mx, sacc[mj][q]);
            mx = fmaxf(mx, __shfl_xor(mx, 1));
            mx = fmaxf(mx, __shfl_xor(mx, 2));
            mx = fmaxf(mx, __shfl_xor(mx, 4));
            mx = fmaxf(mx, __shfl_xor(mx, 8));
            float sm = 0.f;
            #pragma unroll
            for (int mj = 0; mj < 8; ++mj) {
                sacc[mj][q] = __expf(sacc[mj][q] - mx);
                sm += sacc[mj][q];
            }
            sm += __shfl_xor(sm, 1);
            sm += __shfl_xor(sm, 2);
            sm += __shfl_xor(sm, 4);
            sm += __shfl_xor(sm, 8);
            inv[q] = 1.0f / sm;
        }

        // write unnormalized P bf16 to Pn (pair even/odd lanes -> u32 stores); wave-local rows
        #pragma unroll
        for (int mj = 0; mj < 8; ++mj) {
            #pragma unroll
            for (int q = 0; q < 4; ++q) {
                const float pv = sacc[mj][q];
                const float po = __shfl_xor(pv, 1);
                if (!(lane & 1)) {
                    const int n = n0w + 4 * hi + q;
                    const int m = 16 * mj + lr;   // even
                    const unsigned int u = f2bf(pv) | (f2bf(po) << 16);
                    *(unsigned int*)((char*)Pn + n * 256 + ((2 * m) ^ ((n & 7) << 4))) = u;
                }
            }
        }
        // no barrier needed: each wave reads only its own Pn rows (compiler orders same-wave LDS)

        // O = P V : rows n0w..+15, cols d 0..31 (j=0,1)
        f32x4 oacc[2];
        oacc[0] = (f32x4){0.f, 0.f, 0.f, 0.f};
        oacc[1] = (f32x4){0.f, 0.f, 0.f, 0.f};
        const int nA = n0w + lr;                 // A-frag row
        const int swzA = (nA & 7) << 4;
        #pragma unroll
        for (int kk = 0; kk < 4; ++kk) {
            const bf16x8 pa = *(const bf16x8*)((char*)Pn + nA * 256 + ((64 * kk + 16 * hi) ^ swzA));
            #pragma unroll
            for (int j = 0; j < 2; ++j) {
                const int d = j * 16 + lr;
                const bf16x8 vb = *(const bf16x8*)((char*)Vt + d * 256 + ((64 * kk + 16 * hi) ^ ((d & 7) << 4)));
                oacc[j] = __builtin_amdgcn_mfma_f32_16x16x32_bf16(pa, vb, oacc[j], 0, 0, 0);
            }
        }
        // store bf16 into aout (the q region): row n = n0w+4*hi+q, col h*32 + j*16 + lr
        #pragma unroll
        for (int j = 0; j < 2; ++j) {
            #pragma unroll
            for (int q = 0; q < 4; ++q) {
                const int n = n0w + 4 * hi + q;
                aout[((size_t)(w * 64 + n)) * 256 + h * 32 + j * 16 + lr] =
                    (unsigned short)f2bf(oacc[j][q] * inv[q]);
            }
        }
    }
}

extern "C" void kernel_launch(void* const* d_in, const int* in_sizes, int n_in,
                              void* d_out, int out_size, void* d_ws, size_t ws_size,
                              hipStream_t stream)
{
    const float* x      = (const float*)d_in[0];   // (1024,64,256) f32
    const float* x_     = (const float*)d_in[1];   // (1024,128,256) f32
    const int*   mask_l = (const int*)d_in[2];
    const int*   mask_r = (const int*)d_in[3];
    const float* q_w    = (const float*)d_in[5];
    const float* q_b    = (const float*)d_in[6];
    const float* kv_w   = (const float*)d_in[7];
    const float* kv_b   = (const float*)d_in[8];
    const float* proj_w = (const float*)d_in[9];
    const float* proj_b = (const float*)d_in[10];
    const float* bias_t = (const float*)d_in[11];  // (192,8)

    // ws: qbf bf16 [65536][256] (32 MiB; later overwritten with bf16 attn-out) | kvbf bf16 [131072][512] (128 MiB)
    unsigned short* qbf  = (unsigned short*)d_ws;
    unsigned short* kvbf = qbf + (size_t)65536 * 256;
    float* out = (float*)d_out;

    prep_wt<<<1024, 256, 0, stream>>>(q_w, kv_w, proj_w);
    gemm_sa<256, 0,      false, false><<<512,  512, 0, stream>>>(x,  q_b,  qbf);
    gemm_sa<512, 65536,  false, false><<<1024, 512, 0, stream>>>(x_, kv_b, kvbf);
    attn_fused<<<1024, 256, 0, stream>>>(qbf, kvbf, bias_t, mask_l, mask_r, qbf);
    gemm_sa<256, 196608, true,  true ><<<512,  512, 0, stream>>>(qbf, proj_b, out);
}

// Round 7
// 257.498 us; speedup vs baseline: 2.0363x; 2.0363x over previous
//
#include <hip/hip_runtime.h>
#include <float.h>

// B_=1024 windows, N=64, M=128, H=8, D=32, DIM=256, nW=256
// rel bias index: rel = n - m + 128 in [1,191]
// masks: wi in {0,1} -> mask_left[wi], wi in {254,255} -> mask_right[wi-254]

typedef __attribute__((ext_vector_type(8))) short bf16x8;
typedef __attribute__((ext_vector_type(4))) float f32x4;

static __device__ __forceinline__ unsigned int f2bf(float f) {
    unsigned int u = __float_as_uint(f);
    return (u + 0x7FFFu + ((u >> 16) & 1u)) >> 16;  // RNE
}
static __device__ __forceinline__ unsigned int pack2(float lo, float hi) {
    return f2bf(lo) | (f2bf(hi) << 16);
}

// Transposed bf16 weights: [col][k], q @0 (256x256), kv @65536 (512x256), proj @196608 (256x256)
__device__ unsigned short g_Wt[262144];

__global__ __launch_bounds__(256) void prep_wt(
    const float* __restrict__ q_w, const float* __restrict__ kv_w, const float* __restrict__ proj_w)
{
    const int b = blockIdx.x, k = threadIdx.x;
    float v; unsigned short* dst;
    if (b < 256)      { v = q_w[k * 256 + b];            dst = g_Wt + b * 256; }
    else if (b < 768) { v = kv_w[k * 512 + (b - 256)];   dst = g_Wt + 65536 + (b - 256) * 256; }
    else              { v = proj_w[k * 256 + (b - 768)]; dst = g_Wt + 196608 + (b - 768) * 256; }
    dst[k] = (unsigned short)f2bf(v);
}

// ---------- double-buffered MFMA GEMM: C[rows x NC] = A[rows x 256] @ W + bias ----------
// Tile 128x128, BK=64, LDS 2x(16+16)KB = 64KB -> 2 blocks/CU. 512 threads = 8 waves (2x4),
// wave tile 64x32. XCD swizzle: all col-tiles of a row-tile on one XCD (A fetched once, L2-shared).
// LDS XOR swizzle byte ^= ((row&7)<<4) -> conflict-free b128 frag reads.
template<int NC, int WT_OFF, bool ABF16, bool F32OUT>
__global__ __launch_bounds__(512) void gemm_db(
    const void* __restrict__ Ain, const float* __restrict__ bias, void* __restrict__ Cout)
{
    constexpr int NBN = NC / 128;
    __shared__ __align__(16) unsigned short As[2][128 * 64];
    __shared__ __align__(16) unsigned short Ws[2][128 * 64];

    // XCD-aware decode: phys -> (bm, bn) with all bn of one bm on the same XCD (phys%8 const).
    const int nbx = 8 * NBN;
    const int g = blockIdx.x / nbx, r = blockIdx.x % nbx;
    const int bn = r >> 3, bm = g * 8 + (r & 7);
    const size_t r0 = (size_t)bm * 128;
    const int c0 = bn * 128;

    const int t = threadIdx.x;
    const int wave = t >> 6, lane = t & 63;
    const int lr = lane & 15, hi = lane >> 4;
    const int rw = (wave >> 2) * 64, cw = (wave & 3) * 32;   // wave tile origin
    const int srow = t >> 2, sks = (t & 3) * 16;             // staging: row/col, k-segment
    const int aswz = (srow & 7) << 4;
    const int so1 = (2 * sks) ^ aswz, so2 = (2 * sks + 16) ^ aswz;

    f32x4 acc[4][2];
    #pragma unroll
    for (int i = 0; i < 4; ++i)
        #pragma unroll
        for (int j = 0; j < 2; ++j) acc[i][j] = (f32x4){0.f, 0.f, 0.f, 0.f};

    float4 fA0, fA1, fA2, fA3;   // f32 A staging regs
    uint4  sA0, sA1;             // bf16 A staging regs
    uint4  sW0, sW1;             // W staging regs

#define STAGE_LOAD(K0)                                                                     \
    {                                                                                      \
        const unsigned short* wsrc = g_Wt + WT_OFF + (size_t)(c0 + srow) * 256 + (K0) + sks; \
        sW0 = *(const uint4*)wsrc; sW1 = *(const uint4*)(wsrc + 8);                        \
        if (ABF16) {                                                                       \
            const unsigned short* asrc = (const unsigned short*)Ain + (r0 + srow) * 256 + (K0) + sks; \
            sA0 = *(const uint4*)asrc; sA1 = *(const uint4*)(asrc + 8);                    \
        } else {                                                                           \
            const float* asrc = (const float*)Ain + (r0 + srow) * 256 + (K0) + sks;        \
            fA0 = *(const float4*)asrc;       fA1 = *(const float4*)(asrc + 4);            \
            fA2 = *(const float4*)(asrc + 8); fA3 = *(const float4*)(asrc + 12);           \
        }                                                                                  \
    }

#define STAGE_WRITE(B)                                                                     \
    {                                                                                      \
        char* ad = (char*)As[B] + srow * 128;                                              \
        char* wd = (char*)Ws[B] + srow * 128;                                              \
        uint4 u0, u1;                                                                      \
        if (ABF16) { u0 = sA0; u1 = sA1; }                                                 \
        else {                                                                             \
            u0 = make_uint4(pack2(fA0.x, fA0.y), pack2(fA0.z, fA0.w),                      \
                            pack2(fA1.x, fA1.y), pack2(fA1.z, fA1.w));                     \
            u1 = make_uint4(pack2(fA2.x, fA2.y), pack2(fA2.z, fA2.w),                      \
                            pack2(fA3.x, fA3.y), pack2(fA3.z, fA3.w));                     \
        }                                                                                  \
        *(uint4*)(ad + so1) = u0; *(uint4*)(ad + so2) = u1;                                \
        *(uint4*)(wd + so1) = sW0; *(uint4*)(wd + so2) = sW1;                              \
    }

#define COMPUTE(B)                                                                         \
    {                                                                                      \
        const char* Ab = (const char*)As[B];                                               \
        const char* Wb = (const char*)Ws[B];                                               \
        const int swzr = (lr & 7) << 4;                                                    \
        _Pragma("unroll")                                                                  \
        for (int kk = 0; kk < 2; ++kk) {                                                   \
            const int ko = (kk * 64 + hi * 16) ^ swzr;                                     \
            bf16x8 af[4], bf[2];                                                           \
            _Pragma("unroll")                                                              \
            for (int i = 0; i < 4; ++i)                                                    \
                af[i] = *(const bf16x8*)(Ab + (rw + i * 16 + lr) * 128 + ko);              \
            _Pragma("unroll")                                                              \
            for (int j = 0; j < 2; ++j)                                                    \
                bf[j] = *(const bf16x8*)(Wb + (cw + j * 16 + lr) * 128 + ko);              \
            _Pragma("unroll")                                                              \
            for (int i = 0; i < 4; ++i)                                                    \
                _Pragma("unroll")                                                          \
                for (int j = 0; j < 2; ++j)                                                \
                    acc[i][j] = __builtin_amdgcn_mfma_f32_16x16x32_bf16(af[i], bf[j], acc[i][j], 0, 0, 0); \
        }                                                                                  \
    }

    STAGE_LOAD(0); STAGE_WRITE(0); __syncthreads();
    STAGE_LOAD(64);
    COMPUTE(0);
    STAGE_WRITE(1);          // buf1 fresh; others may still read buf0 (disjoint)
    STAGE_LOAD(128);
    __syncthreads();
    COMPUTE(1);
    STAGE_WRITE(0);          // buf0 readers finished before last barrier
    STAGE_LOAD(192);
    __syncthreads();
    COMPUTE(0);
    STAGE_WRITE(1);
    __syncthreads();
    COMPUTE(1);

#undef STAGE_LOAD
#undef STAGE_WRITE
#undef COMPUTE

    // epilogue: row = r0+rw+i*16+4*hi+q, col = c0+cw+bj*16+lr
    #pragma unroll
    for (int i = 0; i < 4; ++i) {
        #pragma unroll
        for (int bj = 0; bj < 2; ++bj) {
            const int col = c0 + cw + bj * 16 + lr;
            const float bb = bias[col];
            #pragma unroll
            for (int q = 0; q < 4; ++q) {
                const size_t row = r0 + rw + i * 16 + 4 * hi + q;
                const float val = acc[i][bj][q] + bb;
                if (F32OUT) ((float*)Cout)[row * NC + col] = val;
                else        ((unsigned short*)Cout)[row * NC + col] = (unsigned short)f2bf(val);
            }
        }
    }
}

// ---------- fused MFMA attention: one block per WINDOW, loop over 8 heads ----------
// Writes bf16 attn output back into the q buffer region (block-local rows -> race-free).
__global__ __launch_bounds__(256) void attn_fused(
    const unsigned short* __restrict__ qbf, const unsigned short* __restrict__ kvbf,
    const float* __restrict__ bias_table, const int* __restrict__ mask_left,
    const int* __restrict__ mask_right, unsigned short* __restrict__ aout)
{
    __shared__ __align__(16) unsigned short Qn[64 * 32];    // [n][d] natural
    __shared__ __align__(16) unsigned short Kn[128 * 32];   // [m][d] natural
    __shared__ __align__(16) unsigned short Vt[32 * 128];   // [d][m], swizzled ^((d&7)<<4)
    __shared__ __align__(16) unsigned short Pn[64 * 128];   // [n][m], swizzled ^((n&7)<<4)
    __shared__ float ballT[8 * 192];                        // bias table [h][rel]

    const int w = blockIdx.x;
    const int t = threadIdx.x;
    const int wave = t >> 6, lane = t & 63;
    const int lr = lane & 15, hi = lane >> 4;
    const int n0w = wave * 16;

    for (int i = t; i < 1536; i += 256) {
        const int hh = i / 192, r = i - hh * 192;
        ballT[i] = bias_table[r * 8 + hh];
    }

    const int wi = w & 255;
    const int* mbase = nullptr;
    if (wi < 2) mbase = mask_left + wi * (64 * 128);
    else if (wi >= 254) mbase = mask_right + (wi - 254) * (64 * 128);

    const float scale = 0.17677669529663687f;  // 32^-0.5

    for (int h = 0; h < 8; ++h) {
        __syncthreads();   // prior iteration's LDS reads complete (and ballT before first use)
        {   // stage Q head-slice: [64][32]
            const int n = t >> 2, dq = t & 3;
            const uint4 v = *(const uint4*)(qbf + ((size_t)(w * 64 + n)) * 256 + h * 32 + dq * 8);
            *(uint4*)((char*)Qn + n * 64 + dq * 16) = v;
        }
        #pragma unroll
        for (int i = 0; i < 2; ++i) {   // stage K: [128][32]
            const int m = (t >> 2) + 64 * i, dq = t & 3;
            const uint4 v = *(const uint4*)(kvbf + ((size_t)(w * 128 + m)) * 512 + h * 32 + dq * 8);
            *(uint4*)((char*)Kn + m * 64 + dq * 16) = v;
        }
        #pragma unroll
        for (int i = 0; i < 2; ++i) {   // stage V transposed: Vt[d][m] swizzled
            const int db = (t >> 7) * 2 + i, m = t & 127;
            const uint4 v = *(const uint4*)(kvbf + ((size_t)(w * 128 + m)) * 512 + 256 + h * 32 + db * 8);
            const unsigned short* vs = (const unsigned short*)&v;
            #pragma unroll
            for (int e = 0; e < 8; ++e) {
                const int d = db * 8 + e;
                *(unsigned short*)((char*)Vt + d * 256 + ((2 * m) ^ ((d & 7) << 4))) = vs[e];
            }
        }
        __syncthreads();

        // S = Q K^T : wave handles rows n0w..n0w+15, all 128 cols
        const bf16x8 qa = *(const bf16x8*)((char*)Qn + (n0w + lr) * 64 + 16 * hi);
        f32x4 sacc[8];
        #pragma unroll
        for (int mj = 0; mj < 8; ++mj) {
            sacc[mj] = (f32x4){0.f, 0.f, 0.f, 0.f};
            const bf16x8 kb = *(const bf16x8*)((char*)Kn + (mj * 16 + lr) * 64 + 16 * hi);
            sacc[mj] = __builtin_amdgcn_mfma_f32_16x16x32_bf16(qa, kb, sacc[mj], 0, 0, 0);
        }

        // epilogue on C-layout: row n = n0w + 4*hi + q, col m = 16*mj + lr
        const float* bh = ballT + h * 192;
        #pragma unroll
        for (int mj = 0; mj < 8; ++mj) {
            const int m = 16 * mj + lr;
            #pragma unroll
            for (int q = 0; q < 4; ++q) {
                const int n = n0w + 4 * hi + q;
                sacc[mj][q] = fmaf(sacc[mj][q], scale, bh[n - m + 128]);
            }
        }
        if (mbase) {
            #pragma unroll
            for (int mj = 0; mj < 8; ++mj) {
                const int m = 16 * mj + lr;
                #pragma unroll
                for (int q = 0; q < 4; ++q) {
                    const int n = n0w + 4 * hi + q;
                    if (mbase[n * 128 + m] == 1) sacc[mj][q] = -FLT_MAX;
                }
            }
        }

        // softmax over m (per row): row lives in 16 lanes sharing hi -> shfl_xor 1,2,4,8
        float inv[4];
        #pragma unroll
        for (int q = 0; q < 4; ++q) {
            float mx = sacc[0][q];
            #pragma unroll
            for (int mj = 1; mj < 8; ++mj) mx = fmaxf(mx, sacc[mj][q]);
            mx = fmaxf(mx, __shfl_xor(mx, 1));
            mx = fmaxf(mx, __shfl_xor(mx, 2));
            mx = fmaxf(mx, __shfl_xor(mx, 4));
            mx = fmaxf(mx, __shfl_xor(mx, 8));
            float sm = 0.f;
            #pragma unroll
            for (int mj = 0; mj < 8; ++mj) {
                sacc[mj][q] = __expf(sacc[mj][q] - mx);
                sm += sacc[mj][q];
            }
            sm += __shfl_xor(sm, 1);
            sm += __shfl_xor(sm, 2);
            sm += __shfl_xor(sm, 4);
            sm += __shfl_xor(sm, 8);
            inv[q] = 1.0f / sm;
        }

        // write unnormalized P bf16 to Pn (pair even/odd lanes -> u32 stores); wave-local rows
        #pragma unroll
        for (int mj = 0; mj < 8; ++mj) {
            #pragma unroll
            for (int q = 0; q < 4; ++q) {
                const float pv = sacc[mj][q];
                const float po = __shfl_xor(pv, 1);
                if (!(lane & 1)) {
                    const int n = n0w + 4 * hi + q;
                    const int m = 16 * mj + lr;   // even
                    const unsigned int u = f2bf(pv) | (f2bf(po) << 16);
                    *(unsigned int*)((char*)Pn + n * 256 + ((2 * m) ^ ((n & 7) << 4))) = u;
                }
            }
        }
        // no barrier needed: each wave reads only its own Pn rows (compiler orders same-wave LDS)

        // O = P V : rows n0w..+15, cols d 0..31 (j=0,1)
        f32x4 oacc[2];
        oacc[0] = (f32x4){0.f, 0.f, 0.f, 0.f};
        oacc[1] = (f32x4){0.f, 0.f, 0.f, 0.f};
        const int nA = n0w + lr;                 // A-frag row
        const int swzA = (nA & 7) << 4;
        #pragma unroll
        for (int kk = 0; kk < 4; ++kk) {
            const bf16x8 pa = *(const bf16x8*)((char*)Pn + nA * 256 + ((64 * kk + 16 * hi) ^ swzA));
            #pragma unroll
            for (int j = 0; j < 2; ++j) {
                const int d = j * 16 + lr;
                const bf16x8 vb = *(const bf16x8*)((char*)Vt + d * 256 + ((64 * kk + 16 * hi) ^ ((d & 7) << 4)));
                oacc[j] = __builtin_amdgcn_mfma_f32_16x16x32_bf16(pa, vb, oacc[j], 0, 0, 0);
            }
        }
        // store bf16 into aout (the q region): row n = n0w+4*hi+q, col h*32 + j*16 + lr
        #pragma unroll
        for (int j = 0; j < 2; ++j) {
            #pragma unroll
            for (int q = 0; q < 4; ++q) {
                const int n = n0w + 4 * hi + q;
                aout[((size_t)(w * 64 + n)) * 256 + h * 32 + j * 16 + lr] =
                    (unsigned short)f2bf(oacc[j][q] * inv[q]);
            }
        }
    }
}

extern "C" void kernel_launch(void* const* d_in, const int* in_sizes, int n_in,
                              void* d_out, int out_size, void* d_ws, size_t ws_size,
                              hipStream_t stream)
{
    const float* x      = (const float*)d_in[0];   // (1024,64,256) f32
    const float* x_     = (const float*)d_in[1];   // (1024,128,256) f32
    const int*   mask_l = (const int*)d_in[2];
    const int*   mask_r = (const int*)d_in[3];
    const float* q_w    = (const float*)d_in[5];
    const float* q_b    = (const float*)d_in[6];
    const float* kv_w   = (const float*)d_in[7];
    const float* kv_b   = (const float*)d_in[8];
    const float* proj_w = (const float*)d_in[9];
    const float* proj_b = (const float*)d_in[10];
    const float* bias_t = (const float*)d_in[11];  // (192,8)

    // ws: qbf bf16 [65536][256] (32 MiB; later overwritten with bf16 attn-out) | kvbf bf16 [131072][512] (128 MiB)
    unsigned short* qbf  = (unsigned short*)d_ws;
    unsigned short* kvbf = qbf + (size_t)65536 * 256;
    float* out = (float*)d_out;

    prep_wt<<<1024, 256, 0, stream>>>(q_w, kv_w, proj_w);
    gemm_db<256, 0,      false, false><<<1024, 512, 0, stream>>>(x,  q_b,  qbf);
    gemm_db<512, 65536,  false, false><<<4096, 512, 0, stream>>>(x_, kv_b, kvbf);
    attn_fused<<<1024, 256, 0, stream>>>(qbf, kvbf, bias_t, mask_l, mask_r, qbf);
    gemm_db<256, 196608, true,  true ><<<1024, 512, 0, stream>>>(qbf, proj_b, out);
}